// Round 5
// baseline (709.260 us; speedup 1.0000x reference)
//
#include <hip/hip_runtime.h>
#include <math.h>

// ---------------------------------------------------------------------------
// HybridGNN on MI355X — R5.
// Kernel 1 (agg L0): gather + mean + 2x[100x50] matvec for all level-0 pairs.
//   Phase C software-pipelined: 4 W float4 loads + 4 X b128 LDS reads per
//   64 FMA, unroll 2 -> ~8 loads in flight (R4 was load-latency-bound).
// Kernel 2 (tail): ONE block per batch row: stages its L0 trees into LDS,
//   computes schema1 L1->L3, schema0 L1, random L1, both attentions,
//   pooling/reflect/L2norm — replaces R4's launches 1-4 entirely.
// ---------------------------------------------------------------------------

#define NBATCH 512
#define TOTALP 1086
#define RPB 32      // rows per agg block
#define XSTR 204    // xs LDS row stride (floats)

struct Seg {
  const float* emb;     // embedding base
  const int*   ids_s;   // self id array
  const int*   ids_n;   // neighbor id array
  const float* Ws;      // [100][50]
  const float* Wn;      // [100][50]
  float*       outp;    // out row j at outp + j*100
  int ss, so;           // self id per-b stride, offset
  int ns, no;           // neigh id per-b stride, offset
  int estride;          // node stride in emb (elements)
  int c;                // self rows per batch element
  int r;                // fanout
  int blk_begin;        // prefix in fused BLOCK space
};

struct KArgs { Seg seg[14]; int n; };

__global__ __launch_bounds__(256) void agg_kernel(KArgs P) {
  __shared__ float xsh[RPB * XSTR];     // 26.1 KB  xs[row][0:100]=s, [100:200]=m
  __shared__ int   ids_s_sh[RPB];
  __shared__ int   ids_n_sh[RPB * 9];

  const int blk = blockIdx.x, tid = threadIdx.x;
  int si = 0;
  for (int i = 1; i < P.n; ++i)
    if (blk >= P.seg[i].blk_begin) si = i;
  const Seg sg = P.seg[si];
  const int j0 = (blk - sg.blk_begin) * RPB;
  const int c = sg.c, r = sg.r;

  // ---- ids staging ----
  if (tid < RPB) {
    int j = j0 + tid, b = j / c, pos = j - b * c;
    ids_s_sh[tid] = sg.ids_s[(long)b * sg.ss + sg.so + pos];
  }
  for (int u = tid; u < RPB * r; u += 256) {
    int row = u / r, q = u - row * r;
    int j = j0 + row, b = j / c, pos = j - b * c;
    ids_n_sh[u] = sg.ids_n[(long)b * sg.ns + sg.no + pos * r + q];
  }
  __syncthreads();

  // ---- Phase B: gather + mean into LDS ----
  const float rinv = 1.f / (float)r;
  for (int u = tid; u < RPB * 25; u += 256) {
    int row = u / 25, q4 = (u - row * 25) * 4;
    const float4 s4 = *(const float4*)(sg.emb + (long)ids_s_sh[row] * sg.estride + q4);
    float mx = 0.f, my = 0.f, mz = 0.f, mw = 0.f;
    for (int rr = 0; rr < r; ++rr) {
      const float4 t = *(const float4*)(sg.emb + (long)ids_n_sh[row * r + rr] * sg.estride + q4);
      mx += t.x; my += t.y; mz += t.z; mw += t.w;
    }
    float4 mv; mv.x = mx * rinv; mv.y = my * rinv; mv.z = mz * rinv; mv.w = mw * rinv;
    *(float4*)&xsh[row * XSTR + q4]       = s4;
    *(float4*)&xsh[row * XSTR + 100 + q4] = mv;
  }
  __syncthreads();

  // ---- Phase C: 4 rows x 4 cols register tiles, pipelined W loads ----
  if (tid < 208) {
    const int rg = tid / 26, hq = tid - rg * 26;
    const int half = hq / 13, q = hq - half * 13;   // q==12 -> cols 48,49 only
    const int col = 4 * q;
    const float* W = half ? sg.Wn : sg.Ws;
    const float* xb = &xsh[(rg * 4) * XSTR + half * 100];
    float acc[4][4];
#pragma unroll
    for (int i = 0; i < 4; ++i) { acc[i][0] = acc[i][1] = acc[i][2] = acc[i][3] = 0.f; }
    if (q < 12) {
#pragma unroll 2
      for (int eb = 0; eb < 100; eb += 4) {
        const float4 w0 = *(const float4*)&W[(eb + 0) * 50 + col];
        const float4 w1 = *(const float4*)&W[(eb + 1) * 50 + col];
        const float4 w2 = *(const float4*)&W[(eb + 2) * 50 + col];
        const float4 w3 = *(const float4*)&W[(eb + 3) * 50 + col];
#pragma unroll
        for (int i = 0; i < 4; ++i) {
          const float4 xv = *(const float4*)&xb[i * XSTR + eb];
          acc[i][0] = fmaf(xv.x, w0.x, acc[i][0]);
          acc[i][0] = fmaf(xv.y, w1.x, acc[i][0]);
          acc[i][0] = fmaf(xv.z, w2.x, acc[i][0]);
          acc[i][0] = fmaf(xv.w, w3.x, acc[i][0]);
          acc[i][1] = fmaf(xv.x, w0.y, acc[i][1]);
          acc[i][1] = fmaf(xv.y, w1.y, acc[i][1]);
          acc[i][1] = fmaf(xv.z, w2.y, acc[i][1]);
          acc[i][1] = fmaf(xv.w, w3.y, acc[i][1]);
          acc[i][2] = fmaf(xv.x, w0.z, acc[i][2]);
          acc[i][2] = fmaf(xv.y, w1.z, acc[i][2]);
          acc[i][2] = fmaf(xv.z, w2.z, acc[i][2]);
          acc[i][2] = fmaf(xv.w, w3.z, acc[i][2]);
          acc[i][3] = fmaf(xv.x, w0.w, acc[i][3]);
          acc[i][3] = fmaf(xv.y, w1.w, acc[i][3]);
          acc[i][3] = fmaf(xv.z, w2.w, acc[i][3]);
          acc[i][3] = fmaf(xv.w, w3.w, acc[i][3]);
        }
      }
    } else {
#pragma unroll 2
      for (int eb = 0; eb < 100; eb += 4) {
        const float2 w0 = *(const float2*)&W[(eb + 0) * 50 + 48];
        const float2 w1 = *(const float2*)&W[(eb + 1) * 50 + 48];
        const float2 w2 = *(const float2*)&W[(eb + 2) * 50 + 48];
        const float2 w3 = *(const float2*)&W[(eb + 3) * 50 + 48];
#pragma unroll
        for (int i = 0; i < 4; ++i) {
          const float4 xv = *(const float4*)&xb[i * XSTR + eb];
          acc[i][0] = fmaf(xv.x, w0.x, acc[i][0]);
          acc[i][0] = fmaf(xv.y, w1.x, acc[i][0]);
          acc[i][0] = fmaf(xv.z, w2.x, acc[i][0]);
          acc[i][0] = fmaf(xv.w, w3.x, acc[i][0]);
          acc[i][1] = fmaf(xv.x, w0.y, acc[i][1]);
          acc[i][1] = fmaf(xv.y, w1.y, acc[i][1]);
          acc[i][1] = fmaf(xv.z, w2.y, acc[i][1]);
          acc[i][1] = fmaf(xv.w, w3.y, acc[i][1]);
        }
      }
    }
    const int ocol = half * 50 + col;
    for (int i = 0; i < 4; ++i) {
      const long j = j0 + rg * 4 + i;
      float* op = sg.outp + j * 100L + ocol;
      if (q < 12) {
        float4 o;
        o.x = fmaxf(acc[i][0], 0.f); o.y = fmaxf(acc[i][1], 0.f);
        o.z = fmaxf(acc[i][2], 0.f); o.w = fmaxf(acc[i][3], 0.f);
        *(float4*)op = o;
      } else {
        float2 o;
        o.x = fmaxf(acc[i][0], 0.f); o.y = fmaxf(acc[i][1], 0.f);
        *(float2*)op = o;
      }
    }
  }
}

// ---------------------------------------------------------------------------
__device__ __forceinline__ float wave_sum_bcast(float p) {
#pragma unroll
  for (int off = 32; off; off >>= 1) p += __shfl_down(p, off);
  return __shfl(p, 0);
}

// A fused aggregation level inside one block's LDS. Rows j in [0,nrows) are
// partitioned into <=3 groups at jb1/jb2; group g has self rows starting sbg,
// neighbor rows starting nbg (r*(j-jbg) stride), fanout rg.
struct LvlMap { int jb1, jb2, sb0, sb1, sb2, nb0, nb1, nb2, r0, r1, r2; };

__device__ __forceinline__ void do_level(
    const float* src, float* dst, float* msh, int nrows, LvlMap m,
    const float* Ws, const float* Wn, int tid)
{
  // means
  for (int u = tid; u < nrows * 25; u += 256) {
    const int j = u / 25, d4 = (u - j * 25) * 4;
    const int g  = (j >= m.jb1) + (j >= m.jb2);
    const int jb = (g == 0) ? 0 : (g == 1 ? m.jb1 : m.jb2);
    const int nb = (g == 0) ? m.nb0 : (g == 1 ? m.nb1 : m.nb2);
    const int r  = (g == 0) ? m.r0 : (g == 1 ? m.r1 : m.r2);
    const int nbase = nb + (j - jb) * r;
    float ax = 0.f, ay = 0.f, az = 0.f, aw = 0.f;
    for (int rr = 0; rr < r; ++rr) {
      const float4 t = *(const float4*)&src[(nbase + rr) * 100 + d4];
      ax += t.x; ay += t.y; az += t.z; aw += t.w;
    }
    const float rinv = 1.f / (float)r;
    float4 o; o.x = ax * rinv; o.y = ay * rinv; o.z = az * rinv; o.w = aw * rinv;
    *(float4*)&msh[j * 100 + d4] = o;
  }
  __syncthreads();
  // matvec + relu
  for (int u = tid; u < nrows * 100; u += 256) {
    const int j = u / 100, o = u - j * 100;
    const int g  = (j >= m.jb1) + (j >= m.jb2);
    const int jb = (g == 0) ? 0 : (g == 1 ? m.jb1 : m.jb2);
    const int sb = (g == 0) ? m.sb0 : (g == 1 ? m.sb1 : m.sb2);
    const int srow = sb + (j - jb);
    const float* x = (o < 50) ? &src[srow * 100] : &msh[j * 100];
    const float* W = (o < 50) ? Ws : Wn;
    const int col = (o < 50) ? o : o - 50;
    float a = 0.f;
#pragma unroll 2
    for (int eb = 0; eb < 100; eb += 4) {
      const float w0 = W[(eb + 0) * 50 + col];
      const float w1 = W[(eb + 1) * 50 + col];
      const float w2 = W[(eb + 2) * 50 + col];
      const float w3 = W[(eb + 3) * 50 + col];
      const float4 xv = *(const float4*)&x[eb];
      a = fmaf(xv.x, w0, a); a = fmaf(xv.y, w1, a);
      a = fmaf(xv.z, w2, a); a = fmaf(xv.w, w3, a);
    }
    dst[j * 100 + o] = fmaxf(a, 0.f);
  }
  __syncthreads();
}

// One block per batch row b, 256 threads: levels 1..3 + attention + epilogue.
__global__ __launch_bounds__(256) void tail_kernel(
    const float* __restrict__ ws,
    const int* __restrict__ nodeids, const int* __restrict__ edgetype,
    const float* __restrict__ base_embed, const float* __restrict__ reflect,
    const float* __restrict__ agg0_self, const float* __restrict__ agg0_neigh,
    const float* __restrict__ agg1_self, const float* __restrict__ agg1_neigh,
    const float* __restrict__ rand_self, const float* __restrict__ rand_neigh,
    const float* __restrict__ vWq, const float* __restrict__ vWk,
    const float* __restrict__ vWv, const float* __restrict__ vWf,
    const float* __restrict__ vg, const float* __restrict__ vb,
    const float* __restrict__ mWq, const float* __restrict__ mWk,
    const float* __restrict__ mWv, const float* __restrict__ mWf,
    const float* __restrict__ mg, const float* __restrict__ mb,
    float* __restrict__ out)
{
  __shared__ float ash[12400];   // level-0 input rows (124 max)
  __shared__ float hsh[1900];    // level-1 rows (19)
  __shared__ float psh[400];     // level-2 rows (4)
  __shared__ float msh[1900];    // mean scratch
  __shared__ float xs[600], lnb[300], qq[300], kk[300], vv[300], ot[300];
  __shared__ float sc[9], musd[6], pooled[100], r200[200], nrmv[1];

  const int b = blockIdx.x, tid = threadIdx.x;
  const int et = edgetype[NBATCH + b];    // edgetype[1][b]
  const int nid = nodeids[b];

  const int C1k[4]  = {1, 3, 15, 105};
  const int CUM1[4] = {0, 1, 4, 19};      // ws row offsets / NBATCH and ash row offs

  // ================= schema1, per t: L1 -> L2 -> L3 =================
  for (int t = 0; t < 2; ++t) {
    const long tbase = (long)t * 147 * NBATCH;
    for (int k = 0; k < 4; ++k) {
      const float* gsrc = ws + (tbase + (long)CUM1[k] * NBATCH + (long)b * C1k[k]) * 100;
      float* ldst = ash + CUM1[k] * 100;
      for (int u = tid; u < C1k[k] * 25; u += 256)
        *(float4*)&ldst[u * 4] = *(const float4*)&gsrc[u * 4];
    }
    __syncthreads();
    // L1: 19 rows; groups: j=0 (r=3), j=1..3 (r=5), j=4..18 (r=7)
    LvlMap m1; m1.jb1 = 1; m1.jb2 = 4;
    m1.sb0 = 0; m1.sb1 = 1; m1.sb2 = 4;
    m1.nb0 = 1; m1.nb1 = 4; m1.nb2 = 19;
    m1.r0 = 3; m1.r1 = 5; m1.r2 = 7;
    do_level(ash, hsh, msh, 19, m1, agg1_self + 5000, agg1_neigh + 5000, tid);
    // L2: 4 rows; j=0 (r=3), j=1..3 (r=5)
    LvlMap m2; m2.jb1 = 1; m2.jb2 = 999;
    m2.sb0 = 0; m2.sb1 = 1; m2.sb2 = 0;
    m2.nb0 = 1; m2.nb1 = 4; m2.nb2 = 0;
    m2.r0 = 3; m2.r1 = 5; m2.r2 = 1;
    do_level(hsh, psh, msh, 4, m2, agg1_self + 10000, agg1_neigh + 10000, tid);
    // L3: 1 row (r=3) -> xs view 1
    LvlMap m3; m3.jb1 = 999; m3.jb2 = 999;
    m3.sb0 = 0; m3.sb1 = 0; m3.sb2 = 0;
    m3.nb0 = 1; m3.nb1 = 0; m3.nb2 = 0;
    m3.r0 = 3; m3.r1 = 1; m3.r2 = 1;
    do_level(psh, xs + 200 + t * 100, msh, 1, m3,
             agg1_self + 15000, agg1_neigh + 15000, tid);
  }

  // ================= schema0, per t: L1 -> xs view 0 =================
  for (int t = 0; t < 2; ++t) {
    const long base = 294L * NBATCH + (long)t * 4 * NBATCH;
    for (int u = tid; u < 25; u += 256)
      *(float4*)&ash[u * 4] = *(const float4*)&ws[(base + b) * 100 + u * 4];
    for (int u = tid; u < 75; u += 256)
      *(float4*)&ash[100 + u * 4] =
          *(const float4*)&ws[(base + NBATCH + (long)b * 3) * 100 + u * 4];
    __syncthreads();
    LvlMap m; m.jb1 = 999; m.jb2 = 999;
    m.sb0 = 0; m.sb1 = 0; m.sb2 = 0; m.nb0 = 1; m.nb1 = 0; m.nb2 = 0;
    m.r0 = 3; m.r1 = 1; m.r2 = 1;
    do_level(ash, xs + t * 100, msh, 1, m, agg0_self + 5000, agg0_neigh + 5000, tid);
  }

  // ================= random: L1 -> xs view 2 (both t) =================
  {
    const long base = 302L * NBATCH;
    for (int u = tid; u < 25; u += 256)
      *(float4*)&ash[u * 4] = *(const float4*)&ws[(base + b) * 100 + u * 4];
    for (int u = tid; u < 75; u += 256)
      *(float4*)&ash[100 + u * 4] =
          *(const float4*)&ws[(base + NBATCH + (long)b * 3) * 100 + u * 4];
    __syncthreads();
    LvlMap m; m.jb1 = 999; m.jb2 = 999;
    m.sb0 = 0; m.sb1 = 0; m.sb2 = 0; m.nb0 = 1; m.nb1 = 0; m.nb2 = 0;
    m.r0 = 3; m.r1 = 1; m.r2 = 1;
    do_level(ash, xs + 400, msh, 1, m, rand_self + 5000, rand_neigh + 5000, tid);
    if (tid < 100) xs[500 + tid] = xs[400 + tid];
    __syncthreads();
  }

  // ---- view attention (seq over t, n=2), query/output row t=et only ----
  for (int v = 0; v < 3; ++v) {
    float* xq = xs + v * 200 + et * 100;
    if (tid < 64) {
      float p = (tid < 50) ? xq[tid] + xq[tid + 50] : 0.f;
      p = wave_sum_bcast(p);
      float mu = p * 0.01f, vr = 0.f;
      if (tid < 50) { float a = xq[tid] - mu, c2 = xq[tid + 50] - mu; vr = a * a + c2 * c2; }
      vr = wave_sum_bcast(vr);
      if (tid == 0) { musd[0] = mu; musd[1] = rsqrtf(vr * 0.01f + 1e-6f); }
    }
    __syncthreads();
    if (tid < 100) lnb[tid] = (xq[tid] - musd[0]) * musd[1] * vg[tid] + vb[tid];
    __syncthreads();
    for (int o = tid; o < 500; o += 256) {
      const int mm = o / 100, d = o - mm * 100;
      const float* xr; const float* W; float* dst;
      if (mm == 0)      { xr = lnb;                           W = vWq; dst = qq; }
      else if (mm <= 2) { xr = xs + v * 200 + (mm - 1) * 100; W = vWk; dst = kk + (mm - 1) * 100; }
      else              { xr = xs + v * 200 + (mm - 3) * 100; W = vWv; dst = vv + (mm - 3) * 100; }
      float a = 0.f;
#pragma unroll 2
      for (int eb = 0; eb < 100; eb += 4) {
        const float w0 = W[(eb + 0) * 100 + d], w1 = W[(eb + 1) * 100 + d];
        const float w2 = W[(eb + 2) * 100 + d], w3 = W[(eb + 3) * 100 + d];
        a = fmaf(xr[eb], w0, a); a = fmaf(xr[eb + 1], w1, a);
        a = fmaf(xr[eb + 2], w2, a); a = fmaf(xr[eb + 3], w3, a);
      }
      dst[d] = a;
    }
    __syncthreads();
    if (tid < 2) {
      float s = 0.f;
      for (int d = 0; d < 100; ++d) s = fmaf(qq[d], kk[tid * 100 + d], s);
      sc[tid] = s * 0.1f;
    }
    __syncthreads();
    if (tid == 0) {
      float mx = fmaxf(sc[0], sc[1]);
      float e0 = __expf(sc[0] - mx), e1 = __expf(sc[1] - mx);
      float inv = 1.f / (e0 + e1);
      sc[0] = e0 * inv; sc[1] = e1 * inv;
    }
    __syncthreads();
    if (tid < 100) ot[tid] = sc[0] * vv[tid] + sc[1] * vv[100 + tid];
    __syncthreads();
    if (tid < 100) {
      float a = 0.f;
      for (int e = 0; e < 100; ++e) a = fmaf(ot[e], vWf[e * 100 + tid], a);
      xq[tid] += a;
    }
    __syncthreads();
  }

  // ---- meta attention (seq over views, n=3) at t=et ----
  {
    const int w = tid >> 6, l = tid & 63;
    if (w < 3) {
      const float* xr = xs + w * 200 + et * 100;
      float p = (l < 50) ? xr[l] + xr[l + 50] : 0.f;
      p = wave_sum_bcast(p);
      float mu = p * 0.01f, vr = 0.f;
      if (l < 50) { float a = xr[l] - mu, c2 = xr[l + 50] - mu; vr = a * a + c2 * c2; }
      vr = wave_sum_bcast(vr);
      if (l == 0) { musd[w * 2] = mu; musd[w * 2 + 1] = rsqrtf(vr * 0.01f + 1e-6f); }
    }
    __syncthreads();
    for (int o = tid; o < 300; o += 256) {
      int i = o / 100, d = o - i * 100;
      lnb[o] = (xs[i * 200 + et * 100 + d] - musd[i * 2]) * musd[i * 2 + 1] * mg[d] + mb[d];
    }
    __syncthreads();
    for (int o = tid; o < 900; o += 256) {
      const int mm = o / 300, rr = (o - mm * 300) / 100, d = o - mm * 300 - rr * 100;
      const float* xr = (mm == 0) ? (lnb + rr * 100) : (xs + rr * 200 + et * 100);
      const float* W  = (mm == 0) ? mWq : (mm == 1 ? mWk : mWv);
      float a = 0.f;
#pragma unroll 2
      for (int eb = 0; eb < 100; eb += 4) {
        const float w0 = W[(eb + 0) * 100 + d], w1 = W[(eb + 1) * 100 + d];
        const float w2 = W[(eb + 2) * 100 + d], w3 = W[(eb + 3) * 100 + d];
        a = fmaf(xr[eb], w0, a); a = fmaf(xr[eb + 1], w1, a);
        a = fmaf(xr[eb + 2], w2, a); a = fmaf(xr[eb + 3], w3, a);
      }
      float* dst = (mm == 0) ? qq : (mm == 1 ? kk : vv);
      dst[rr * 100 + d] = a;
    }
    __syncthreads();
    if (tid < 9) {
      int i = tid / 3, u = tid - i * 3;
      float s = 0.f;
      for (int d = 0; d < 100; ++d) s = fmaf(qq[i * 100 + d], kk[u * 100 + d], s);
      sc[tid] = s * 0.1f;
    }
    __syncthreads();
    if (tid < 3) {
      float mx = fmaxf(sc[tid * 3], fmaxf(sc[tid * 3 + 1], sc[tid * 3 + 2]));
      float e0 = __expf(sc[tid * 3] - mx), e1 = __expf(sc[tid * 3 + 1] - mx),
            e2 = __expf(sc[tid * 3 + 2] - mx);
      float inv = 1.f / (e0 + e1 + e2);
      sc[tid * 3] = e0 * inv; sc[tid * 3 + 1] = e1 * inv; sc[tid * 3 + 2] = e2 * inv;
    }
    __syncthreads();
    for (int o = tid; o < 300; o += 256) {
      int i = o / 100, d = o - i * 100;
      ot[o] = sc[i * 3] * vv[d] + sc[i * 3 + 1] * vv[100 + d] + sc[i * 3 + 2] * vv[200 + d];
    }
    __syncthreads();
    for (int o = tid; o < 300; o += 256) {
      int i = o / 100, d = o - i * 100;
      float a = 0.f;
      for (int e = 0; e < 100; ++e) a = fmaf(ot[i * 100 + e], mWf[e * 100 + d], a);
      lnb[o] = a;
    }
    __syncthreads();
    for (int o = tid; o < 300; o += 256) {
      int i = o / 100, d = o - i * 100;
      xs[i * 200 + et * 100 + d] += lnb[o];
    }
    __syncthreads();
  }

  // ---- pool over views (t=et), reflect, residual, L2 norm ----
  if (tid < 100)
    pooled[tid] = (xs[et * 100 + tid] + xs[200 + et * 100 + tid] +
                   xs[400 + et * 100 + tid]) * (1.f / 3.f);
  __syncthreads();
  if (tid < 200) {
    float a = base_embed[(long)nid * 200 + tid];
    const float* rf = reflect + (long)et * 20000 + tid;   // reflect[et][d][o]
#pragma unroll 2
    for (int d = 0; d < 100; ++d) a = fmaf(pooled[d], rf[d * 200], a);
    r200[tid] = a;
  }
  __syncthreads();
  if (tid < 64) {
    float p = r200[tid] * r200[tid] + r200[tid + 64] * r200[tid + 64]
            + r200[tid + 128] * r200[tid + 128];
    if (tid < 8) p += r200[tid + 192] * r200[tid + 192];
    p = wave_sum_bcast(p);
    if (tid == 0) nrmv[0] = 1.f / fmaxf(sqrtf(p), 1e-12f);
  }
  __syncthreads();
  if (tid < 200) out[(long)b * 200 + tid] = r200[tid] * nrmv[0];
}

// ---------------------------------------------------------------------------
extern "C" void kernel_launch(void* const* d_in, const int* in_sizes, int n_in,
                              void* d_out, int out_size, void* d_ws, size_t ws_size,
                              hipStream_t stream) {
  (void)in_sizes; (void)n_in; (void)out_size; (void)ws_size;
  const int*   nodeids          = (const int*)d_in[0];
  const int*   edgetype         = (const int*)d_in[1];
  const int*   neighbors        = (const int*)d_in[2];
  const int*   random_neighbors = (const int*)d_in[3];
  const float* base_embed       = (const float*)d_in[4];
  const float* type_embed       = (const float*)d_in[5];
  const float* rw_embed         = (const float*)d_in[6];
  const float* reflect          = (const float*)d_in[7];
  const float* agg0_self        = (const float*)d_in[8];
  const float* agg0_neigh       = (const float*)d_in[9];
  const float* agg1_self        = (const float*)d_in[10];
  const float* agg1_neigh       = (const float*)d_in[11];
  const float* rand_self        = (const float*)d_in[12];
  const float* rand_neigh       = (const float*)d_in[13];
  const float* vWq = (const float*)d_in[14];
  const float* vWk = (const float*)d_in[15];
  const float* vWv = (const float*)d_in[16];
  const float* vWf = (const float*)d_in[17];
  const float* vg  = (const float*)d_in[18];
  const float* vb  = (const float*)d_in[19];
  const float* mWq = (const float*)d_in[20];
  const float* mWk = (const float*)d_in[21];
  const float* mWv = (const float*)d_in[22];
  const float* mWf = (const float*)d_in[23];
  const float* mg  = (const float*)d_in[24];
  const float* mb  = (const float*)d_in[25];

  float* ws = (float*)d_ws;
  const long S1r = 147L * NBATCH;
  auto rp = [&](long rows) { return ws + rows * 100; };

  const int  OFF1[4] = {18, 21, 36, 141};
  const int  FAN1[4] = {3, 5, 7, 9};
  const int  C1[4]   = {1, 3, 15, 105};
  const long CUM1[4] = {0, 1, 4, 19};

  KArgs A; long acc = 0;   // blocks of RPB rows
  auto addg = [&](const float* emb, int estride,
                  const int* isrc, int ss, int so, int c,
                  const int* insrc, int nstr, int no, int r,
                  const float* Ws, const float* Wn, float* outp) {
    Seg& s = A.seg[A.n++];
    s.emb = emb; s.ids_s = isrc; s.ids_n = insrc;
    s.Ws = Ws; s.Wn = Wn; s.outp = outp;
    s.ss = ss; s.so = so; s.ns = nstr; s.no = no;
    s.estride = estride; s.c = c; s.r = r; s.blk_begin = (int)acc;
    acc += (long)c * NBATCH / RPB;
  };

  // ---- launch 0: all level-0 (gather) pairs ----
  A.n = 0; acc = 0;
  for (int t = 0; t < 2; ++t)
    for (int k = 0; k < 4; ++k) {
      const float* emb = type_embed + (t * 2 + 1) * 100;  // (t, idx=1)
      if (k == 0)
        addg(emb, 400, nodeids, 1, 0, 1,
             neighbors, 2 * TOTALP, t * TOTALP + OFF1[k], FAN1[k],
             agg1_self, agg1_neigh, rp(t * S1r + CUM1[k] * NBATCH));
      else
        addg(emb, 400, neighbors, 2 * TOTALP, t * TOTALP + OFF1[k - 1], C1[k],
             neighbors, 2 * TOTALP, t * TOTALP + OFF1[k], FAN1[k],
             agg1_self, agg1_neigh, rp(t * S1r + CUM1[k] * NBATCH));
    }
  for (int t = 0; t < 2; ++t)
    for (int k = 0; k < 2; ++k) {
      const float* emb = type_embed + (t * 2 + 0) * 100;  // (t, idx=0)
      long obase = 294L * NBATCH + (long)t * 4 * NBATCH + (k == 0 ? 0 : 1) * NBATCH;
      if (k == 0)
        addg(emb, 400, nodeids, 1, 0, 1,
             neighbors, 2 * TOTALP, t * TOTALP + 0, 3,
             agg0_self, agg0_neigh, rp(obase));
      else
        addg(emb, 400, neighbors, 2 * TOTALP, t * TOTALP + 0, 3,
             neighbors, 2 * TOTALP, t * TOTALP + 3, 5,
             agg0_self, agg0_neigh, rp(obase));
    }
  for (int k = 0; k < 2; ++k) {
    long obase = 302L * NBATCH + (k == 0 ? 0 : 1) * NBATCH;
    if (k == 0)
      addg(rw_embed, 100, nodeids, 1, 0, 1,
           random_neighbors, 18, 0, 3, rand_self, rand_neigh, rp(obase));
    else
      addg(rw_embed, 100, random_neighbors, 18, 0, 3,
           random_neighbors, 18, 3, 5, rand_self, rand_neigh, rp(obase));
  }
  agg_kernel<<<dim3((unsigned)acc), dim3(256), 0, stream>>>(A);

  // ---- launch 1: fused tail (levels 1-3 + attention + epilogue) ----
  tail_kernel<<<dim3(NBATCH), dim3(256), 0, stream>>>(
      ws, nodeids, edgetype, base_embed, reflect,
      agg0_self, agg0_neigh, agg1_self, agg1_neigh, rand_self, rand_neigh,
      vWq, vWk, vWv, vWf, vg, vb, mWq, mWk, mWv, mWf, mg, mb,
      (float*)d_out);
}